// Round 3
// baseline (478.476 us; speedup 1.0000x reference)
//
#include <hip/hip_runtime.h>

#define BLOCK 256
#define UNROLL 8
#define CHUNK (BLOCK * UNROLL)   // float4 elements per block

// Native clang vector type: __builtin_nontemporal_load requires a vector of
// scalar type, not HIP's HIP_vector_type<float,4> class. Layout-identical.
typedef float vfloat4 __attribute__((ext_vector_type(4)));

// Mahalanobis AR(1) loss:
//   quad[b] = sum d_i^2 + 2*coef*sum d_i*d_{i+1},  d = (y_true-y_pred)*mask(t<n[b])
//   out = mean_b quad[b]/n[b]
// D = 64 floats = 16 float4/row; lane handles col4 = tid&15.
//
// R3: sched_barrier(0) pins all 17 vmem ops per thread BEFORE any compute.
// R5: nontemporal loads via native ext_vector_type(4) (compile-fixed R4).
// R6 (this round): identical resubmit -- R5 never ran (GPU acquisition
// timeout); we need a measurement before changing anything else.
__global__ __launch_bounds__(BLOCK) void mahal_main(
    const vfloat4* __restrict__ yt4,
    const vfloat4* __restrict__ yp4,
    const float*  __restrict__ param,
    const int*    __restrict__ n,
    float* __restrict__ partial,
    int total_vec4)
{
    float t = param[0];
    float p = 2.0f / (1.0f + __expf(-t)) - 1.0f;
    float coef2 = -2.0f * p / (1.0f + p * p);   // 2*coef

    int base = blockIdx.x * CHUNK + (int)threadIdx.x;

    vfloat4 a[UNROLL], b[UNROLL];
    int     vv[UNROLL];

    if ((blockIdx.x + 1) * CHUNK <= total_vec4) {
        // fast path (block-uniform): all loads in range, no clamping
        #pragma unroll
        for (int j = 0; j < UNROLL; ++j) {
            int g = base + j * BLOCK;
            a[j]  = __builtin_nontemporal_load(&yt4[g]);
            b[j]  = __builtin_nontemporal_load(&yp4[g]);
            vv[j] = n[g >> 4];
        }
    } else {
        #pragma unroll
        for (int j = 0; j < UNROLL; ++j) {
            int gj = base + j * BLOCK;
            int g  = gj < total_vec4 ? gj : 0;
            a[j]  = __builtin_nontemporal_load(&yt4[g]);
            b[j]  = __builtin_nontemporal_load(&yp4[g]);
            vv[j] = (gj < total_vec4) ? n[g >> 4] : 0;   // 0 => masked out below
        }
    }
    // Forbid the scheduler from sinking loads into the compute loop:
    __builtin_amdgcn_sched_barrier(0);

    int col4 = threadIdx.x & 15;
    int e0   = col4 << 2;
    bool not_last = (col4 != 15);
    float acc = 0.0f;

    #pragma unroll
    for (int j = 0; j < UNROLL; ++j) {
        int v = vv[j];
        float d0 = (e0 + 0 < v) ? (a[j].x - b[j].x) : 0.0f;
        float d1 = (e0 + 1 < v) ? (a[j].y - b[j].y) : 0.0f;
        float d2 = (e0 + 2 < v) ? (a[j].z - b[j].z) : 0.0f;
        float d3 = (e0 + 3 < v) ? (a[j].w - b[j].w) : 0.0f;
        // boundary pair (e0+3, e0+4): neighbor lane's d0; lane col4==15 is row end
        float nb = __shfl_down(d0, 1, 64);
        float sumsq = d0 * d0 + d1 * d1 + d2 * d2 + d3 * d3;
        float cross = d0 * d1 + d1 * d2 + d2 * d3;
        if (not_last) cross += d3 * nb;
        float q  = fmaf(coef2, cross, sumsq);
        // v==0 (tail) => q==0; avoid 0*rcp(0)=NaN by clamping divisor to 1
        float rv = __builtin_amdgcn_rcpf((float)(v > 0 ? v : 1));
        acc = fmaf(q, rv, acc);
    }

    // wave reduction (64 lanes)
    #pragma unroll
    for (int off = 32; off >= 1; off >>= 1)
        acc += __shfl_down(acc, off, 64);

    __shared__ float smem[BLOCK / 64];
    int lane = threadIdx.x & 63;
    int wid  = threadIdx.x >> 6;
    if (lane == 0) smem[wid] = acc;
    __syncthreads();
    if (threadIdx.x == 0) {
        float s = 0.0f;
        #pragma unroll
        for (int i = 0; i < BLOCK / 64; ++i) s += smem[i];
        partial[blockIdx.x] = s;
    }
}

// Single-block reduction of per-block partials; writes the final mean.
__global__ __launch_bounds__(256) void mahal_finish(
    const float* __restrict__ partial,
    float* __restrict__ out,
    int nblocks, float invB)
{
    float acc = 0.0f;
    if ((nblocks & 3) == 0) {
        const float4* p4 = (const float4*)partial;
        int n4 = nblocks >> 2;
        for (int i = threadIdx.x; i < n4; i += 256) {
            float4 v = p4[i];
            acc += v.x + v.y + v.z + v.w;
        }
    } else {
        for (int i = threadIdx.x; i < nblocks; i += 256)
            acc += partial[i];
    }
    #pragma unroll
    for (int off = 32; off >= 1; off >>= 1)
        acc += __shfl_down(acc, off, 64);
    __shared__ float smem[4];
    int lane = threadIdx.x & 63;
    int wid  = threadIdx.x >> 6;
    if (lane == 0) smem[wid] = acc;
    __syncthreads();
    if (threadIdx.x == 0)
        out[0] = (smem[0] + smem[1] + smem[2] + smem[3]) * invB;
}

extern "C" void kernel_launch(void* const* d_in, const int* in_sizes, int n_in,
                              void* d_out, int out_size, void* d_ws, size_t ws_size,
                              hipStream_t stream) {
    const float* y_true = (const float*)d_in[0];
    const float* y_pred = (const float*)d_in[1];
    const float* param  = (const float*)d_in[2];
    const int*   n      = (const int*)d_in[3];
    float* out = (float*)d_out;

    int total = in_sizes[0];        // B*D
    int B     = in_sizes[3];        // rows
    int total_vec4 = total / 4;
    float invB = 1.0f / (float)B;

    int blocks = (total_vec4 + CHUNK - 1) / CHUNK;   // 8192 at B=1M, D=64
    float* partial = (float*)d_ws;                   // needs blocks*4 bytes

    mahal_main<<<blocks, BLOCK, 0, stream>>>((const vfloat4*)y_true,
                                             (const vfloat4*)y_pred,
                                             param, n, partial, total_vec4);
    mahal_finish<<<1, 256, 0, stream>>>(partial, out, blocks, invB);
}

// Round 8
// 476.736 us; speedup vs baseline: 1.0036x; 1.0036x over previous
//
#include <hip/hip_runtime.h>

#define BLOCK 256
#define UNROLL 8
#define CHUNK (BLOCK * UNROLL)   // float4 elements per block

// Native clang vector type: __builtin_nontemporal_load requires a vector of
// scalar type, not HIP's HIP_vector_type<float,4> class. Layout-identical.
typedef float vfloat4 __attribute__((ext_vector_type(4)));

// Mahalanobis AR(1) loss:
//   quad[b] = sum d_i^2 + 2*coef*sum d_i*d_{i+1},  d = (y_true-y_pred)*mask(t<n[b])
//   out = mean_b quad[b]/n[b]
// D = 64 floats = 16 float4/row; lane handles col4 = tid&15.
//
// R3: sched_barrier(0) pins all vmem ops BEFORE any compute.
// R5: nontemporal loads on the two read-once streams (verified: 505->478 us).
// R7: LDS-stage n[] -- removes 8 redundant cached dword loads per thread from
// the nt-stream burst; global stream becomes pure dwordx4 nt. n-load+barrier
// issued BEFORE the stream loads so the barrier's vmcnt(0) drains nothing.
// R11 (this round): identical resubmit -- R7/R8/R9/R10 never ran (GPU
// acquisition timeouts x4); measurement needed before any further change.
__global__ __launch_bounds__(BLOCK) void mahal_main(
    const vfloat4* __restrict__ yt4,
    const vfloat4* __restrict__ yp4,
    const float*  __restrict__ param,
    const int*    __restrict__ n,
    float* __restrict__ partial,
    int total_vec4)
{
    float t = param[0];
    float p = 2.0f / (1.0f + __expf(-t)) - 1.0f;
    float coef2 = -2.0f * p / (1.0f + p * p);   // 2*coef

    const int tid  = (int)threadIdx.x;
    const int base = blockIdx.x * CHUNK + tid;

    vfloat4 a[UNROLL], b[UNROLL];
    int     vv[UNROLL];

    __shared__ int lds_n[CHUNK / 16];   // 128 rows per block

    if ((blockIdx.x + 1) * CHUNK <= total_vec4) {
        // fast path (block-uniform): all loads in range, no clamping.
        // Stage this block's 128 n values first (single int4 per 32 threads).
        if (tid < (CHUNK / 16) / 4) {
            const int4* n4 = (const int4*)(n + blockIdx.x * (CHUNK / 16));
            ((int4*)lds_n)[tid] = n4[tid];
        }
        __syncthreads();   // nothing in vmem queue yet besides the int4 above

        #pragma unroll
        for (int j = 0; j < UNROLL; ++j) {
            int g = base + j * BLOCK;
            a[j]  = __builtin_nontemporal_load(&yt4[g]);
            b[j]  = __builtin_nontemporal_load(&yp4[g]);
        }
        // Forbid the scheduler from sinking loads into the compute loop:
        __builtin_amdgcn_sched_barrier(0);

        int r0 = tid >> 4;                 // row within block for j=0
        #pragma unroll
        for (int j = 0; j < UNROLL; ++j)
            vv[j] = lds_n[r0 + 16 * j];    // lanes 0-15 broadcast, no conflicts
    } else {
        #pragma unroll
        for (int j = 0; j < UNROLL; ++j) {
            int gj = base + j * BLOCK;
            int g  = gj < total_vec4 ? gj : 0;
            a[j]  = __builtin_nontemporal_load(&yt4[g]);
            b[j]  = __builtin_nontemporal_load(&yp4[g]);
            vv[j] = (gj < total_vec4) ? n[g >> 4] : 0;   // 0 => masked out below
        }
        __builtin_amdgcn_sched_barrier(0);
    }

    int col4 = tid & 15;
    int e0   = col4 << 2;
    bool not_last = (col4 != 15);
    float acc = 0.0f;

    #pragma unroll
    for (int j = 0; j < UNROLL; ++j) {
        int v = vv[j];
        float d0 = (e0 + 0 < v) ? (a[j].x - b[j].x) : 0.0f;
        float d1 = (e0 + 1 < v) ? (a[j].y - b[j].y) : 0.0f;
        float d2 = (e0 + 2 < v) ? (a[j].z - b[j].z) : 0.0f;
        float d3 = (e0 + 3 < v) ? (a[j].w - b[j].w) : 0.0f;
        // boundary pair (e0+3, e0+4): neighbor lane's d0; lane col4==15 is row end
        float nb = __shfl_down(d0, 1, 64);
        float sumsq = d0 * d0 + d1 * d1 + d2 * d2 + d3 * d3;
        float cross = d0 * d1 + d1 * d2 + d2 * d3;
        if (not_last) cross += d3 * nb;
        float q  = fmaf(coef2, cross, sumsq);
        // v==0 (tail) => q==0; avoid 0*rcp(0)=NaN by clamping divisor to 1
        float rv = __builtin_amdgcn_rcpf((float)(v > 0 ? v : 1));
        acc = fmaf(q, rv, acc);
    }

    // wave reduction (64 lanes)
    #pragma unroll
    for (int off = 32; off >= 1; off >>= 1)
        acc += __shfl_down(acc, off, 64);

    __shared__ float smem[BLOCK / 64];
    int lane = tid & 63;
    int wid  = tid >> 6;
    if (lane == 0) smem[wid] = acc;
    __syncthreads();
    if (tid == 0) {
        float s = 0.0f;
        #pragma unroll
        for (int i = 0; i < BLOCK / 64; ++i) s += smem[i];
        partial[blockIdx.x] = s;
    }
}

// Single-block reduction of per-block partials; writes the final mean.
__global__ __launch_bounds__(256) void mahal_finish(
    const float* __restrict__ partial,
    float* __restrict__ out,
    int nblocks, float invB)
{
    float acc = 0.0f;
    if ((nblocks & 3) == 0) {
        const float4* p4 = (const float4*)partial;
        int n4 = nblocks >> 2;
        for (int i = threadIdx.x; i < n4; i += 256) {
            float4 v = p4[i];
            acc += v.x + v.y + v.z + v.w;
        }
    } else {
        for (int i = threadIdx.x; i < nblocks; i += 256)
            acc += partial[i];
    }
    #pragma unroll
    for (int off = 32; off >= 1; off >>= 1)
        acc += __shfl_down(acc, off, 64);
    __shared__ float smem[4];
    int lane = threadIdx.x & 63;
    int wid  = threadIdx.x >> 6;
    if (lane == 0) smem[wid] = acc;
    __syncthreads();
    if (threadIdx.x == 0)
        out[0] = (smem[0] + smem[1] + smem[2] + smem[3]) * invB;
}

extern "C" void kernel_launch(void* const* d_in, const int* in_sizes, int n_in,
                              void* d_out, int out_size, void* d_ws, size_t ws_size,
                              hipStream_t stream) {
    const float* y_true = (const float*)d_in[0];
    const float* y_pred = (const float*)d_in[1];
    const float* param  = (const float*)d_in[2];
    const int*   n      = (const int*)d_in[3];
    float* out = (float*)d_out;

    int total = in_sizes[0];        // B*D
    int B     = in_sizes[3];        // rows
    int total_vec4 = total / 4;
    float invB = 1.0f / (float)B;

    int blocks = (total_vec4 + CHUNK - 1) / CHUNK;   // 8192 at B=1M, D=64
    float* partial = (float*)d_ws;                   // needs blocks*4 bytes

    mahal_main<<<blocks, BLOCK, 0, stream>>>((const vfloat4*)y_true,
                                             (const vfloat4*)y_pred,
                                             param, n, partial, total_vec4);
    mahal_finish<<<1, 256, 0, stream>>>(partial, out, blocks, invB);
}